// Round 5
// baseline (43.034 us; speedup 1.0000x reference)
//
#include <hip/hip_runtime.h>
#include <math.h>

// CorticalMicrocircuit: dy = f(params, t, y, drive). Elementwise over B circuits.
// out rows 0..5 = y rows 6..11; out rows 6..11 = drive + M·F(y[0..5]) - damping.
// Memory-bound: 201 MB r+w -> ~32 us floor. Round 5: single fused kernel
// (setup-kernel node cost ~3.7 us serial per replay -> removed), preamble
// parallelized across 72 lanes, 8 elems/thread in two coalesced panels.

typedef float v4f __attribute__((ext_vector_type(4)));

// Lane-indexed tables must live in device memory (function-local runtime-indexed
// arrays go to scratch). CIDX[i*6+j] = param index of coupling coeff feeding
// F_j into output row i; 255 = structural zero.
__device__ const unsigned char CIDX[36] = {
    0, 255,  18,  27,  37, 255,
    1,  10,  19,  28,  38, 255,
    2,  11, 255,  29, 255, 255,
    3,  12,  21,  30,  39,  46,
    4,  13,  22,  31,  40,  47,
    5, 255, 255,  32,  41,  48
};
__device__ const unsigned char GIDX[6] = {6, 14, 23, 33, 42, 49};   // a/b rate
__device__ const unsigned char NIDX[6] = {53, 54, 55, 56, 57, 58};  // N_pop
__device__ const unsigned char RIDX[6] = {9, 17, 26, 36, 45, 52};   // r
__device__ const unsigned char VIDX[6] = {8, 16, 25, 35, 44, 51};   // v0
__device__ const unsigned char EIDX[6] = {7, 15, 24, 34, 43, 50};   // e0

// sc layout: [0..5]=r, [6..11]=r*v0, [12..17]=2*e0, [18..23]=2*g,
//            [24..29]=g^2, [30..35]=drive row, [36..71]=M[6][6]
__device__ __forceinline__ void compute6(const v4f* __restrict__ v,
                                         const float* __restrict__ sc,
                                         float* __restrict__ out,
                                         size_t base, size_t n)
{
    float F[6][4];
#pragma unroll
    for (int k = 0; k < 6; ++k) {
        const float rk  = sc[k];
        const float rv0 = sc[6 + k];
        const float e2  = sc[12 + k];
#pragma unroll
        for (int j = 0; j < 4; ++j)
            F[k][j] = e2 / (1.0f + __expf(rv0 - rk * v[k][j]));
    }
#pragma unroll
    for (int i = 0; i < 6; ++i) {
        const float dr  = sc[30 + i];
        const float tg  = sc[18 + i];
        const float gsq = sc[24 + i];
        v4f o;
#pragma unroll
        for (int j = 0; j < 4; ++j) {
            float acc = dr;
#pragma unroll
            for (int k = 0; k < 6; ++k)
                acc = fmaf(sc[36 + i * 6 + k], F[k][j], acc);
            acc = fmaf(-tg, v[6 + i][j], acc);
            acc = fmaf(-gsq, v[i][j], acc);
            o[j] = acc;
        }
        *(v4f*)(out + (size_t)(6 + i) * n + base) = o;
    }
}

__global__ __launch_bounds__(256) void cc_kernel(
    const float* __restrict__ params,
    const float* __restrict__ blo,
    const float* __restrict__ bhi,
    const float* __restrict__ tptr,
    const float* __restrict__ y,
    const float* __restrict__ drive,
    float* __restrict__ out,
    int n, int tsteps)
{
    __shared__ float p[59];
    __shared__ float sc[72];
    const int tid = threadIdx.x;

    if (tid < 59)
        p[tid] = fminf(fmaxf(params[tid], blo[tid]), bhi[tid]);
    __syncthreads();

    // one lane per derived scalar (~15 instrs each, no serial section)
    if (tid < 72) {
        float v;
        if (tid < 6) {
            v = p[RIDX[tid]];
        } else if (tid < 12) {
            const int k = tid - 6;  v = p[RIDX[k]] * p[VIDX[k]];
        } else if (tid < 18) {
            const int k = tid - 12; v = 2.0f * p[EIDX[k]];
        } else if (tid < 24) {
            const int k = tid - 18; v = 2.0f * p[GIDX[k]];
        } else if (tid < 30) {
            const int k = tid - 24; const float g = p[GIDX[k]]; v = g * g;
        } else if (tid < 36) {
            const int k = tid - 30;
            const float t = *tptr;
            const float fi = fminf(fmaxf(t / 0.002f, 0.0f), (float)(tsteps - 1));
            const int ti = (int)fi;   // truncation matches astype(int32)
            v = drive[(size_t)ti * 6 + k];
        } else {
            const int l = tid - 36;
            const int i = l / 6, j = l - i * 6;
            const int c = CIDX[l];
            if (c == 255) {
                v = 0.0f;
            } else {
                float m = p[c] * p[GIDX[j]];
                if (i != j) m = m * (p[NIDX[j]] / p[NIDX[i]]);  // diag has no ratio
                if (j >= 3) m = -m;                              // B-type inhibitory
                v = m;
            }
        }
        sc[tid] = v;
    }
    __syncthreads();

    const size_t n_ = (size_t)n;
    const size_t b0 = (size_t)blockIdx.x * 2048 + (size_t)tid * 4;
    const size_t b1 = b0 + 1024;
    if (b0 >= n_) return;
    const bool do1 = (b1 + 3 < n_);

    // Load both panels' 12 state rows up front (max loads in flight)
    v4f va[12], vb[12];
#pragma unroll
    for (int r = 0; r < 12; ++r)
        va[r] = *(const v4f*)(y + (size_t)r * n_ + b0);
    if (do1) {
#pragma unroll
        for (int r = 0; r < 12; ++r)
            vb[r] = *(const v4f*)(y + (size_t)r * n_ + b1);
    }

    // out rows 0..5 = y rows 6..11 (pass-through)
#pragma unroll
    for (int r = 0; r < 6; ++r)
        *(v4f*)(out + (size_t)r * n_ + b0) = va[6 + r];
    if (do1) {
#pragma unroll
        for (int r = 0; r < 6; ++r)
            *(v4f*)(out + (size_t)r * n_ + b1) = vb[6 + r];
    }

    compute6(va, sc, out, b0, n_);
    if (do1) compute6(vb, sc, out, b1, n_);
}

extern "C" void kernel_launch(void* const* d_in, const int* in_sizes, int n_in,
                              void* d_out, int out_size, void* d_ws, size_t ws_size,
                              hipStream_t stream) {
    const float* params = (const float*)d_in[0];
    const float* blo    = (const float*)d_in[1];
    const float* bhi    = (const float*)d_in[2];
    const float* tptr   = (const float*)d_in[3];
    const float* y      = (const float*)d_in[4];
    const float* drive  = (const float*)d_in[5];
    float* out = (float*)d_out;

    const int n      = in_sizes[4] / 12;   // B
    const int tsteps = in_sizes[5] / 6;    // T

    const int threads = 256;
    const int elems_per_block = threads * 8;                        // two panels
    const int blocks = (n + elems_per_block - 1) / elems_per_block; // 1024 for B=2^21

    cc_kernel<<<blocks, threads, 0, stream>>>(params, blo, bhi, tptr, y, drive,
                                              out, n, tsteps);
}

// Round 6
// 37.317 us; speedup vs baseline: 1.1532x; 1.1532x over previous
//
#include <hip/hip_runtime.h>
#include <math.h>

// CorticalMicrocircuit: dy = f(params, t, y, drive). Elementwise over B circuits.
// out rows 0..5 = y rows 6..11; out rows 6..11 = drive + M·F(y[0..5]) - damping.
// Memory-bound (latency/occupancy-limited: fabric ~4 TB/s < 6.3 ceiling).
// Round 6: round-1 structure (4 elems/thread, VGPR~48, occupancy ~38%) +
// round-5's parallelized 72-lane preamble. VGPR pressure is the key invariant:
// round 5 showed 120 VGPR / 19% occupancy costs 5 us on this kernel.

typedef float v4f __attribute__((ext_vector_type(4)));

// CIDX[i*6+j] = param index of coupling coeff feeding F_j into output row 6+i;
// 255 = structural zero. Diagonal entries have no N-ratio; j>=3 (B-type) negate.
__device__ const unsigned char CIDX[36] = {
    0, 255,  18,  27,  37, 255,
    1,  10,  19,  28,  38, 255,
    2,  11, 255,  29, 255, 255,
    3,  12,  21,  30,  39,  46,
    4,  13,  22,  31,  40,  47,
    5, 255, 255,  32,  41,  48
};
__device__ const unsigned char GIDX[6] = {6, 14, 23, 33, 42, 49};   // a/b rate
__device__ const unsigned char NIDX[6] = {53, 54, 55, 56, 57, 58};  // N_pop
__device__ const unsigned char RIDX[6] = {9, 17, 26, 36, 45, 52};   // r
__device__ const unsigned char VIDX[6] = {8, 16, 25, 35, 44, 51};   // v0
__device__ const unsigned char EIDX[6] = {7, 15, 24, 34, 43, 50};   // e0

__global__ __launch_bounds__(256) void cc_kernel(
    const float* __restrict__ params,
    const float* __restrict__ blo,
    const float* __restrict__ bhi,
    const float* __restrict__ tptr,
    const float* __restrict__ y,
    const float* __restrict__ drive,
    float* __restrict__ out,
    int n, int tsteps)
{
    // sc layout: [0..5]=r, [6..11]=r*v0, [12..17]=2*e0, [18..23]=2*g,
    //            [24..29]=g^2, [30..35]=drive row, [36..71]=M[6][6]
    __shared__ float p[59];
    __shared__ float sc[72];
    const int tid = threadIdx.x;

    if (tid < 59)
        p[tid] = fminf(fmaxf(params[tid], blo[tid]), bhi[tid]);
    __syncthreads();

    // one lane per derived scalar (~15 instrs/lane, no serial section)
    if (tid < 72) {
        float v;
        if (tid < 6) {
            v = p[RIDX[tid]];
        } else if (tid < 12) {
            const int k = tid - 6;  v = p[RIDX[k]] * p[VIDX[k]];
        } else if (tid < 18) {
            const int k = tid - 12; v = 2.0f * p[EIDX[k]];
        } else if (tid < 24) {
            const int k = tid - 18; v = 2.0f * p[GIDX[k]];
        } else if (tid < 30) {
            const int k = tid - 24; const float g = p[GIDX[k]]; v = g * g;
        } else if (tid < 36) {
            const int k = tid - 30;
            const float t = *tptr;
            const float fi = fminf(fmaxf(t / 0.002f, 0.0f), (float)(tsteps - 1));
            const int ti = (int)fi;   // truncation matches astype(int32)
            v = drive[(size_t)ti * 6 + k];
        } else {
            const int l = tid - 36;
            const int i = l / 6, j = l - i * 6;
            const int c = CIDX[l];
            if (c == 255) {
                v = 0.0f;
            } else {
                float m = p[c] * p[GIDX[j]];
                if (i != j) m = m * (p[NIDX[j]] / p[NIDX[i]]);  // diag has no ratio
                if (j >= 3) m = -m;                              // B-type inhibitory
                v = m;
            }
        }
        sc[tid] = v;
    }
    __syncthreads();

    const size_t n_ = (size_t)n;
    const size_t i4 = ((size_t)blockIdx.x * blockDim.x + threadIdx.x) * 4;
    if (i4 >= n_) return;

    // Load all 12 state rows (16B per row)
    v4f v[12];
#pragma unroll
    for (int r = 0; r < 12; ++r)
        v[r] = *(const v4f*)(y + (size_t)r * n_ + i4);

    // out rows 0..5 = y rows 6..11 (pass-through)
#pragma unroll
    for (int r = 0; r < 6; ++r)
        *(v4f*)(out + (size_t)r * n_ + i4) = v[6 + r];

    // Sigmoid firing rates F[pop][elem] = 2*e0 / (1 + exp(r*v0 - r*v))
    float F[6][4];
#pragma unroll
    for (int k = 0; k < 6; ++k) {
        const float rk  = sc[k];
        const float rv0 = sc[6 + k];
        const float e2  = sc[12 + k];
#pragma unroll
        for (int j = 0; j < 4; ++j)
            F[k][j] = e2 / (1.0f + __expf(rv0 - rk * v[k][j]));
    }

    // out rows 6..11
#pragma unroll
    for (int i = 0; i < 6; ++i) {
        const float dr  = sc[30 + i];
        const float tg  = sc[18 + i];
        const float gsq = sc[24 + i];
        v4f o;
#pragma unroll
        for (int j = 0; j < 4; ++j) {
            float acc = dr;
#pragma unroll
            for (int k = 0; k < 6; ++k)
                acc = fmaf(sc[36 + i * 6 + k], F[k][j], acc);
            acc = fmaf(-tg, v[6 + i][j], acc);
            acc = fmaf(-gsq, v[i][j], acc);
            o[j] = acc;
        }
        *(v4f*)(out + (size_t)(6 + i) * n_ + i4) = o;
    }
}

extern "C" void kernel_launch(void* const* d_in, const int* in_sizes, int n_in,
                              void* d_out, int out_size, void* d_ws, size_t ws_size,
                              hipStream_t stream) {
    const float* params = (const float*)d_in[0];
    const float* blo    = (const float*)d_in[1];
    const float* bhi    = (const float*)d_in[2];
    const float* tptr   = (const float*)d_in[3];
    const float* y      = (const float*)d_in[4];
    const float* drive  = (const float*)d_in[5];
    float* out = (float*)d_out;

    const int n      = in_sizes[4] / 12;   // B
    const int tsteps = in_sizes[5] / 6;    // T

    const int threads = 256;
    const int elems_per_block = threads * 4;
    const int blocks = (n + elems_per_block - 1) / elems_per_block;  // 2048 for B=2^21

    cc_kernel<<<blocks, threads, 0, stream>>>(params, blo, bhi, tptr, y, drive,
                                              out, n, tsteps);
}

// Round 7
// 36.669 us; speedup vs baseline: 1.1736x; 1.0177x over previous
//
#include <hip/hip_runtime.h>
#include <math.h>

// CorticalMicrocircuit: dy = f(params, t, y, drive). Elementwise over B circuits.
// out rows 0..5 = y rows 6..11; out rows 6..11 = drive + M·F(y[0..5]) - damping.
// Memory-bound. Round 7: round-6 structure (best: 37.3 us, VGPR 48, occ 38%)
// + v_rcp_f32 instead of full-precision divide (cuts ~150 VALU instrs/thread
// off the post-load critical path) + 128-thread blocks for finer scheduling.

typedef float v4f __attribute__((ext_vector_type(4)));

// CIDX[i*6+j] = param index of coupling coeff feeding F_j into output row 6+i;
// 255 = structural zero. Diagonal entries have no N-ratio; j>=3 (B-type) negate.
__device__ const unsigned char CIDX[36] = {
    0, 255,  18,  27,  37, 255,
    1,  10,  19,  28,  38, 255,
    2,  11, 255,  29, 255, 255,
    3,  12,  21,  30,  39,  46,
    4,  13,  22,  31,  40,  47,
    5, 255, 255,  32,  41,  48
};
__device__ const unsigned char GIDX[6] = {6, 14, 23, 33, 42, 49};   // a/b rate
__device__ const unsigned char NIDX[6] = {53, 54, 55, 56, 57, 58};  // N_pop
__device__ const unsigned char RIDX[6] = {9, 17, 26, 36, 45, 52};   // r
__device__ const unsigned char VIDX[6] = {8, 16, 25, 35, 44, 51};   // v0
__device__ const unsigned char EIDX[6] = {7, 15, 24, 34, 43, 50};   // e0

__global__ __launch_bounds__(128) void cc_kernel(
    const float* __restrict__ params,
    const float* __restrict__ blo,
    const float* __restrict__ bhi,
    const float* __restrict__ tptr,
    const float* __restrict__ y,
    const float* __restrict__ drive,
    float* __restrict__ out,
    int n, int tsteps)
{
    // sc layout: [0..5]=r, [6..11]=r*v0, [12..17]=2*e0, [18..23]=2*g,
    //            [24..29]=g^2, [30..35]=drive row, [36..71]=M[6][6]
    __shared__ float p[59];
    __shared__ float sc[72];
    const int tid = threadIdx.x;

    if (tid < 59)
        p[tid] = fminf(fmaxf(params[tid], blo[tid]), bhi[tid]);
    __syncthreads();

    // one lane per derived scalar (~15 instrs/lane, no serial section)
    if (tid < 72) {
        float v;
        if (tid < 6) {
            v = p[RIDX[tid]];
        } else if (tid < 12) {
            const int k = tid - 6;  v = p[RIDX[k]] * p[VIDX[k]];
        } else if (tid < 18) {
            const int k = tid - 12; v = 2.0f * p[EIDX[k]];
        } else if (tid < 24) {
            const int k = tid - 18; v = 2.0f * p[GIDX[k]];
        } else if (tid < 30) {
            const int k = tid - 24; const float g = p[GIDX[k]]; v = g * g;
        } else if (tid < 36) {
            const int k = tid - 30;
            const float t = *tptr;
            const float fi = fminf(fmaxf(t / 0.002f, 0.0f), (float)(tsteps - 1));
            const int ti = (int)fi;   // truncation matches astype(int32)
            v = drive[(size_t)ti * 6 + k];
        } else {
            const int l = tid - 36;
            const int i = l / 6, j = l - i * 6;
            const int c = CIDX[l];
            if (c == 255) {
                v = 0.0f;
            } else {
                float m = p[c] * p[GIDX[j]];
                if (i != j) m = m * (p[NIDX[j]] / p[NIDX[i]]);  // diag has no ratio
                if (j >= 3) m = -m;                              // B-type inhibitory
                v = m;
            }
        }
        sc[tid] = v;
    }
    __syncthreads();

    const size_t n_ = (size_t)n;
    const size_t i4 = ((size_t)blockIdx.x * blockDim.x + threadIdx.x) * 4;
    if (i4 >= n_) return;

    // Load all 12 state rows (16B per row)
    v4f v[12];
#pragma unroll
    for (int r = 0; r < 12; ++r)
        v[r] = *(const v4f*)(y + (size_t)r * n_ + i4);

    // out rows 0..5 = y rows 6..11 (pass-through)
#pragma unroll
    for (int r = 0; r < 6; ++r)
        *(v4f*)(out + (size_t)r * n_ + i4) = v[6 + r];

    // Sigmoid firing rates F = 2*e0 * rcp(1 + exp(r*v0 - r*v)); v_rcp_f32
    // rel-err ~1e-5 on O(100) values -> abs err << 117.76 threshold.
    float F[6][4];
#pragma unroll
    for (int k = 0; k < 6; ++k) {
        const float rk  = sc[k];
        const float rv0 = sc[6 + k];
        const float e2  = sc[12 + k];
#pragma unroll
        for (int j = 0; j < 4; ++j)
            F[k][j] = e2 * __builtin_amdgcn_rcpf(1.0f + __expf(rv0 - rk * v[k][j]));
    }

    // out rows 6..11
#pragma unroll
    for (int i = 0; i < 6; ++i) {
        const float dr  = sc[30 + i];
        const float tg  = sc[18 + i];
        const float gsq = sc[24 + i];
        v4f o;
#pragma unroll
        for (int j = 0; j < 4; ++j) {
            float acc = dr;
#pragma unroll
            for (int k = 0; k < 6; ++k)
                acc = fmaf(sc[36 + i * 6 + k], F[k][j], acc);
            acc = fmaf(-tg, v[6 + i][j], acc);
            acc = fmaf(-gsq, v[i][j], acc);
            o[j] = acc;
        }
        *(v4f*)(out + (size_t)(6 + i) * n_ + i4) = o;
    }
}

extern "C" void kernel_launch(void* const* d_in, const int* in_sizes, int n_in,
                              void* d_out, int out_size, void* d_ws, size_t ws_size,
                              hipStream_t stream) {
    const float* params = (const float*)d_in[0];
    const float* blo    = (const float*)d_in[1];
    const float* bhi    = (const float*)d_in[2];
    const float* tptr   = (const float*)d_in[3];
    const float* y      = (const float*)d_in[4];
    const float* drive  = (const float*)d_in[5];
    float* out = (float*)d_out;

    const int n      = in_sizes[4] / 12;   // B
    const int tsteps = in_sizes[5] / 6;    // T

    const int threads = 128;
    const int elems_per_block = threads * 4;
    const int blocks = (n + elems_per_block - 1) / elems_per_block;  // 4096 for B=2^21

    cc_kernel<<<blocks, threads, 0, stream>>>(params, blo, bhi, tptr, y, drive,
                                              out, n, tsteps);
}